// Round 2
// baseline (282.378 us; speedup 1.0000x reference)
//
#include <hip/hip_runtime.h>
#include <hip/hip_bf16.h>
#include <hip/hip_fp16.h>

#define N_NODES 50000
#define N_EDGES 800000
#define HDIM 128
#define NGRAPH 512
#define NCLS 10
#define BN_EPS 1e-5f
#define MAXDEG 64   // in-deg ~ Poisson(16) over 50k bins; P(any>=64) ~ 1e-14

typedef unsigned int   uint32;
typedef unsigned short u16;
typedef __attribute__((ext_vector_type(8))) _Float16 half8;  // 8 fp16 (4 VGPRs)
typedef __attribute__((ext_vector_type(4))) float f32x4;

// fp32 -> fp16 bits (round-to-nearest-even)
__device__ inline u16 f2h(float f) {
    return __half_as_ushort(__float2half(f));
}
__device__ inline float h2f(u16 u) {
    return __half2float(__ushort_as_half(u));
}
// fp16x2 (packed in a uint) -> float2
__device__ inline float2 h2f2(uint32 u) {
    __half2 h = *(__half2*)&u;
    return __half22float2(h);
}
__device__ inline uint32 packh2(float lo, float hi) {
    return (uint32)f2h(lo) | ((uint32)f2h(hi) << 16);
}

#define W2T_BLOCKS 8
#define G1_BLOCKS 782                       // ceil(50000/64) rows of 64
#define FRONT_GRID (W2T_BLOCKS + 5 * G1_BLOCKS)   // 8 + 3910 = 3918
#define BT_STRIDE 144

// ---------------------------------------------------------------------------
// Fused front kernel. Role by blockIdx:
//   [0,8)            : W2 -> W2t fp16 transpose-convert (for MFMA gemm2)
//   rem==0 of rest   : gemm1 via fp16 MFMA, hi/lo split (x @ W1 -> bufA fp16)
//   rem==1..4        : bucket_edges (atomic-bound, VALU ~0) -- co-scheduled
// gemm1 accuracy: x = A_hi + A_lo, W1 = B_hi + B_lo (fp16 residual split);
// acc = A_hi*B_hi + A_lo*B_hi + A_hi*B_lo -> fp32-equivalent (err ~2^-21).
// ---------------------------------------------------------------------------
__global__ __launch_bounds__(256) void front(const float* __restrict__ x,
                                             const float* __restrict__ W1,
                                             u16* __restrict__ bufA,
                                             const int* __restrict__ src,
                                             const int* __restrict__ dst,
                                             int* __restrict__ deg,
                                             u16* __restrict__ epad,
                                             const float* __restrict__ W2,
                                             u16* __restrict__ W2t)
{
    __shared__ u16 bt_hi[HDIM * BT_STRIDE];   // 36.9 KB
    __shared__ u16 bt_lo[HDIM * BT_STRIDE];   // 36.9 KB  (2 blocks/CU total)
    const int tid = threadIdx.x;
    int bid = blockIdx.x;

    if (bid < W2T_BLOCKS) {
        // W2t[n][k] = fp16(W2[k][n]); 16384 elems over 2048 threads
        int t0 = bid * 256 + tid;
        for (int i = t0; i < HDIM * HDIM; i += W2T_BLOCKS * 256) {
            int k = i >> 7, n = i & 127;
            W2t[n * HDIM + k] = f2h(W2[i]);
        }
        return;
    }
    bid -= W2T_BLOCKS;
    const int grp = bid / 5, rem = bid % 5;

    if (rem != 0) {
        // ---- bucket_edges ----
        int e = (grp * 4 + (rem - 1)) * 256 + tid;
        if (e < N_EDGES) {
            int d   = dst[e];
            int pos = atomicAdd(&deg[d], 1);
            epad[d * MAXDEG + pos] = (u16)src[e];
        }
        return;
    }

    // ---- gemm1 via MFMA: stage W1^T hi/lo fp16 into LDS ----
    for (int ii = tid; ii < HDIM * HDIM / 4; ii += 256) {
        int i = ii << 2;                      // 4 consecutive n, same k
        float4 w = *(const float4*)(W1 + i);
        int k = i >> 7, nn = i & 127;
        u16 h0 = f2h(w.x), h1 = f2h(w.y), h2 = f2h(w.z), h3 = f2h(w.w);
        bt_hi[(nn + 0) * BT_STRIDE + k] = h0;
        bt_hi[(nn + 1) * BT_STRIDE + k] = h1;
        bt_hi[(nn + 2) * BT_STRIDE + k] = h2;
        bt_hi[(nn + 3) * BT_STRIDE + k] = h3;
        bt_lo[(nn + 0) * BT_STRIDE + k] = f2h(w.x - h2f(h0));
        bt_lo[(nn + 1) * BT_STRIDE + k] = f2h(w.y - h2f(h1));
        bt_lo[(nn + 2) * BT_STRIDE + k] = f2h(w.z - h2f(h2));
        bt_lo[(nn + 3) * BT_STRIDE + k] = f2h(w.w - h2f(h3));
    }
    __syncthreads();

    const int wave = tid >> 6, lane = tid & 63;
    const int rowbase = grp * 64 + wave * 16;
    if (rowbase >= N_NODES) return;           // 50000 % 16 == 0: whole strips
    const int n = lane & 15, q = lane >> 4;

    half8 a_hi[4], a_lo[4];
    const float* arow = x + (size_t)(rowbase + n) * HDIM;
    #pragma unroll
    for (int kc = 0; kc < 4; ++kc) {
        float4 lo4 = *(const float4*)(arow + kc * 32 + q * 8);
        float4 hi4 = *(const float4*)(arow + kc * 32 + q * 8 + 4);
        float f[8] = {lo4.x, lo4.y, lo4.z, lo4.w, hi4.x, hi4.y, hi4.z, hi4.w};
        half8 ah, al;
        #pragma unroll
        for (int e = 0; e < 8; ++e) {
            _Float16 h = (_Float16)f[e];
            ah[e] = h;
            al[e] = (_Float16)(f[e] - (float)h);
        }
        a_hi[kc] = ah; a_lo[kc] = al;
    }

    #pragma unroll
    for (int t = 0; t < 8; ++t) {
        f32x4 acc = {0.f, 0.f, 0.f, 0.f};
        #pragma unroll
        for (int kc = 0; kc < 4; ++kc) {
            half8 bh = *(const half8*)&bt_hi[(t * 16 + n) * BT_STRIDE + kc * 32 + q * 8];
            half8 bl = *(const half8*)&bt_lo[(t * 16 + n) * BT_STRIDE + kc * 32 + q * 8];
            acc = __builtin_amdgcn_mfma_f32_16x16x32_f16(a_hi[kc], bh, acc, 0, 0, 0);
            acc = __builtin_amdgcn_mfma_f32_16x16x32_f16(a_lo[kc], bh, acc, 0, 0, 0);
            acc = __builtin_amdgcn_mfma_f32_16x16x32_f16(a_hi[kc], bl, acc, 0, 0, 0);
        }
        #pragma unroll
        for (int r = 0; r < 4; ++r) {
            int grow = rowbase + q * 4 + r;   // C/D: col=lane&15, row=quad*4+reg
            bufA[(size_t)grow * HDIM + t * 16 + n] = f2h(acc[r]);
        }
    }
}

// ---------------------------------------------------------------------------
// Layer-2 GEMM via fp16 MFMA 16x16x32.  Y[n][:] = A[n][:] @ W2  (A,Y fp16).
// W2t is pre-transposed fp16 [n][k].  Block: 256 thr = 4 waves x 16 rows.
// B staged in LDS, stride 144 (slot-uniform for ds_read_b128);
// A-fragments straight from global (16B/lane, sector-coalesced).
// ---------------------------------------------------------------------------
__global__ __launch_bounds__(256) void gemm2_mfma(const u16* __restrict__ A,
                                                  const u16* __restrict__ W2t,
                                                  u16* __restrict__ Y, int nrows)
{
    __shared__ u16 bt[HDIM * BT_STRIDE];
    const int tid = threadIdx.x;
    // stage W2t (dense 128x128 fp16) -> LDS stride 144, vectorized 16B
    for (int i = tid; i < HDIM * HDIM / 8; i += 256) {
        int n  = i >> 4;
        int k8 = (i & 15) << 3;
        *(uint4*)&bt[n * BT_STRIDE + k8] = *(const uint4*)&W2t[n * HDIM + k8];
    }
    __syncthreads();

    const int wave = tid >> 6, lane = tid & 63;
    const int rowbase = blockIdx.x * 64 + wave * 16;
    if (rowbase >= nrows) return;                   // 50000 % 16 == 0: whole strips
    const int n = lane & 15, q = lane >> 4;

    half8 a[4];
    const u16* arow = A + (size_t)(rowbase + n) * HDIM;
    #pragma unroll
    for (int kc = 0; kc < 4; ++kc)
        a[kc] = *(const half8*)(arow + kc * 32 + q * 8);

    #pragma unroll
    for (int t = 0; t < 8; ++t) {
        f32x4 acc = {0.f, 0.f, 0.f, 0.f};
        #pragma unroll
        for (int kc = 0; kc < 4; ++kc) {
            half8 b = *(const half8*)&bt[(t * 16 + n) * BT_STRIDE + kc * 32 + q * 8];
            acc = __builtin_amdgcn_mfma_f32_16x16x32_f16(a[kc], b, acc, 0, 0, 0);
        }
        #pragma unroll
        for (int r = 0; r < 4; ++r) {
            int grow = rowbase + q * 4 + r;          // C/D: col=lane&15, row=quad*4+reg
            Y[(size_t)grow * HDIM + t * 16 + n] = f2h(acc[r]);
        }
    }
}

// ---------------------------------------------------------------------------
// Padded-bucket gather + self-loop + bias + BN(eval) + ReLU, fused. fp16 h.
// One node/wave; quarter-wave per edge (lane: 8 channels, 16B load);
// 2x unrolled (8 edges in flight); per-edge rsqrt fused (no dis array).
// ---------------------------------------------------------------------------
__global__ __launch_bounds__(256) void gather_bn_relu(const u16* __restrict__ h,
                                                      const u16* __restrict__ epad,
                                                      const int* __restrict__ deg,
                                                      const float* __restrict__ b,
                                                      const float* __restrict__ gamma,
                                                      const float* __restrict__ beta,
                                                      const float* __restrict__ mean,
                                                      const float* __restrict__ var,
                                                      u16* __restrict__ out, int n)
{
    int node = blockIdx.x * 4 + (threadIdx.x >> 6);
    if (node >= n) return;
    const int lane = threadIdx.x & 63;
    const int q    = lane >> 4;          // quarter: which edge of the 4
    const int ci   = (lane & 15) << 3;   // 8 channels per lane
    const int cnt_e = deg[node];
    const float dd  = rsqrtf((float)cnt_e + 1.0f);

    // self-row load early (independent, hides latency)
    uint4 hv = *(const uint4*)(h + (size_t)node * HDIM + ci);

    // preload this node's edge list: lane l owns edge l (cnt_e <= 64)
    int   s_all  = 0;
    float nm_all = 0.f;
    if (lane < cnt_e) {
        s_all  = epad[node * MAXDEG + lane];
        nm_all = rsqrtf((float)deg[s_all] + 1.0f) * dd;
    }

    float acc[8] = {0.f, 0.f, 0.f, 0.f, 0.f, 0.f, 0.f, 0.f};
    int j = q;
    for (; j + 4 < cnt_e; j += 8) {
        int   s0 = __shfl(s_all, j);     float nm0 = __shfl(nm_all, j);
        int   s1 = __shfl(s_all, j + 4); float nm1 = __shfl(nm_all, j + 4);
        uint4 v0 = *(const uint4*)(h + (size_t)s0 * HDIM + ci);
        uint4 v1 = *(const uint4*)(h + (size_t)s1 * HDIM + ci);
        float2 f0 = h2f2(v0.x), f1 = h2f2(v0.y), f2 = h2f2(v0.z), f3 = h2f2(v0.w);
        acc[0] += f0.x * nm0; acc[1] += f0.y * nm0;
        acc[2] += f1.x * nm0; acc[3] += f1.y * nm0;
        acc[4] += f2.x * nm0; acc[5] += f2.y * nm0;
        acc[6] += f3.x * nm0; acc[7] += f3.y * nm0;
        float2 g0 = h2f2(v1.x), g1 = h2f2(v1.y), g2 = h2f2(v1.z), g3 = h2f2(v1.w);
        acc[0] += g0.x * nm1; acc[1] += g0.y * nm1;
        acc[2] += g1.x * nm1; acc[3] += g1.y * nm1;
        acc[4] += g2.x * nm1; acc[5] += g2.y * nm1;
        acc[6] += g3.x * nm1; acc[7] += g3.y * nm1;
    }
    if (j < cnt_e) {
        int   s0 = __shfl(s_all, j); float nm0 = __shfl(nm_all, j);
        uint4 v0 = *(const uint4*)(h + (size_t)s0 * HDIM + ci);
        float2 f0 = h2f2(v0.x), f1 = h2f2(v0.y), f2 = h2f2(v0.z), f3 = h2f2(v0.w);
        acc[0] += f0.x * nm0; acc[1] += f0.y * nm0;
        acc[2] += f1.x * nm0; acc[3] += f1.y * nm0;
        acc[4] += f2.x * nm0; acc[5] += f2.y * nm0;
        acc[6] += f3.x * nm0; acc[7] += f3.y * nm0;
    }
    #pragma unroll
    for (int k = 0; k < 8; ++k) {
        acc[k] += __shfl_xor(acc[k], 16);
        acc[k] += __shfl_xor(acc[k], 32);
    }

    if (q == 0) {
        float2 g0 = h2f2(hv.x), g1 = h2f2(hv.y), g2 = h2f2(hv.z), g3 = h2f2(hv.w);
        float dd2 = dd * dd;
        float a[8] = {acc[0] + g0.x * dd2, acc[1] + g0.y * dd2,
                      acc[2] + g1.x * dd2, acc[3] + g1.y * dd2,
                      acc[4] + g2.x * dd2, acc[5] + g2.y * dd2,
                      acc[6] + g3.x * dd2, acc[7] + g3.y * dd2};
        float o[8];
        #pragma unroll
        for (int k = 0; k < 8; ++k) {
            int c = ci + k;
            float sc = gamma[c] * rsqrtf(var[c] + BN_EPS);
            float r  = (a[k] + b[c] - mean[c]) * sc + beta[c];
            o[k] = fmaxf(r, 0.f);
        }
        uint4 ov;
        ov.x = packh2(o[0], o[1]); ov.y = packh2(o[2], o[3]);
        ov.z = packh2(o[4], o[5]); ov.w = packh2(o[6], o[7]);
        *(uint4*)(out + (size_t)node * HDIM + ci) = ov;
    }
}

// ---------------------------------------------------------------------------
// Pool: sums[batch[n]][c] += h[n][c] (fp16 h, fp32 sums); batch sorted.
// Also accumulates per-graph node counts (thread 0 of each block).
// ---------------------------------------------------------------------------
__global__ __launch_bounds__(128) void pool_sum(const u16* __restrict__ h,
                                                const int* __restrict__ batch,
                                                float* __restrict__ sums,
                                                float* __restrict__ cnt, int n)
{
    int c  = threadIdx.x;
    int n0 = blockIdx.x * 32;
    if (n0 >= n) return;
    int nend = min(n0 + 32, n);
    int curg = batch[n0];
    float acc = 0.f;
    int run = 0;
    for (int i = n0; i < nend; ++i) {
        int g   = batch[i];
        float v = __half2float(__ushort_as_half(h[(size_t)i * HDIM + c]));
        if (g != curg) {
            atomicAdd(&sums[(size_t)curg * HDIM + c], acc);
            if (c == 0) atomicAdd(&cnt[curg], (float)run);
            acc = 0.f; run = 0; curg = g;
        }
        acc += v; run++;
    }
    atomicAdd(&sums[(size_t)curg * HDIM + c], acc);
    if (c == 0) atomicAdd(&cnt[curg], (float)run);
}

// ---------------------------------------------------------------------------
// out[g][c] = (sums[g]/max(cnt[g],1)) . Wlin[:,c] + blin[c]
// ---------------------------------------------------------------------------
__global__ __launch_bounds__(128) void final_lin(const float* __restrict__ sums,
                                                 const float* __restrict__ cnt,
                                                 const float* __restrict__ Wlin,
                                                 const float* __restrict__ blin,
                                                 float* __restrict__ out)
{
    __shared__ float red[NCLS][2];
    int g = blockIdx.x;
    int t = threadIdx.x;
    float ic = 1.f / fmaxf(cnt[g], 1.f);
    float v  = sums[(size_t)g * HDIM + t] * ic;
    float p[NCLS];
    #pragma unroll
    for (int c = 0; c < NCLS; ++c) p[c] = v * Wlin[t * NCLS + c];
    #pragma unroll
    for (int c = 0; c < NCLS; ++c) {
        float x = p[c];
        for (int off = 32; off > 0; off >>= 1) x += __shfl_down(x, off);
        if ((t & 63) == 0) red[c][t >> 6] = x;
    }
    __syncthreads();
    if (t < NCLS) out[g * NCLS + t] = red[t][0] + red[t][1] + blin[t];
}

// ---------------------------------------------------------------------------
extern "C" void kernel_launch(void* const* d_in, const int* in_sizes, int n_in,
                              void* d_out, int out_size, void* d_ws, size_t ws_size,
                              hipStream_t stream)
{
    const float* x     = (const float*)d_in[0];
    const int*   ei    = (const int*)d_in[1];
    const int*   srcp  = ei;
    const int*   dstp  = ei + N_EDGES;
    const int*   batch = (const int*)d_in[2];
    const float* W1    = (const float*)d_in[3];
    const float* b1    = (const float*)d_in[4];
    const float* g1    = (const float*)d_in[5];
    const float* be1   = (const float*)d_in[6];
    const float* m1    = (const float*)d_in[7];
    const float* v1    = (const float*)d_in[8];
    const float* W2    = (const float*)d_in[9];
    const float* b2    = (const float*)d_in[10];
    const float* g2    = (const float*)d_in[11];
    const float* be2   = (const float*)d_in[12];
    const float* m2    = (const float*)d_in[13];
    const float* v2    = (const float*)d_in[14];
    const float* Wlin  = (const float*)d_in[15];
    const float* blin  = (const float*)d_in[16];
    float*       out   = (float*)d_out;

    // workspace layout (~32.5 MiB):
    // [deg int | cnt f32 | sums f32]  <- one contiguous zeroed region
    // bufA fp16 | bufB fp16 | epad u16 | W2t fp16
    int*   deg  = (int*)d_ws;
    float* cnt  = (float*)(deg + N_NODES);
    float* sums = cnt + NGRAPH;
    u16*   bufA = (u16*)(sums + (size_t)NGRAPH * HDIM);
    u16*   bufB = bufA + (size_t)N_NODES * HDIM;
    u16*   epad = bufB + (size_t)N_NODES * HDIM;
    u16*   W2t  = epad + (size_t)N_NODES * MAXDEG;

    hipMemsetAsync(deg, 0,
                   (N_NODES + NGRAPH + (size_t)NGRAPH * HDIM) * sizeof(float), stream);

    // ---- fused front: bucket + gemm1(MFMA hi/lo) + W2 transpose ----
    front<<<FRONT_GRID, 256, 0, stream>>>(x, W1, bufA, srcp, dstp, deg, epad, W2, W2t);

    const int gather_blocks = (N_NODES + 3) / 4;

    // ---- layer 1 aggregation ----
    gather_bn_relu<<<gather_blocks, 256, 0, stream>>>(bufA, epad, deg,
                                                      b1, g1, be1, m1, v1, bufB, N_NODES);
    // ---- layer 2 ----
    gemm2_mfma<<<(N_NODES + 63) / 64, 256, 0, stream>>>(bufB, W2t, bufA, N_NODES);
    gather_bn_relu<<<gather_blocks, 256, 0, stream>>>(bufA, epad, deg,
                                                      b2, g2, be2, m2, v2, bufB, N_NODES);
    // ---- pool + head ----
    pool_sum<<<(N_NODES + 31) / 32, 128, 0, stream>>>(bufB, batch, sums, cnt, N_NODES);
    final_lin<<<NGRAPH, 128, 0, stream>>>(sums, cnt, Wlin, blin, out);
}

// Round 4
// 274.456 us; speedup vs baseline: 1.0289x; 1.0289x over previous
//
#include <hip/hip_runtime.h>
#include <hip/hip_bf16.h>
#include <hip/hip_fp16.h>

#define N_NODES 50000
#define N_EDGES 800000
#define HDIM 128
#define NGRAPH 512
#define NCLS 10
#define BN_EPS 1e-5f
#define MAXDEG 64   // in-deg ~ Poisson(16) over 50k bins; P(any>=64) ~ 1e-14

typedef unsigned int   uint32;
typedef unsigned short u16;
typedef __attribute__((ext_vector_type(8))) _Float16 half8;  // 8 fp16 (4 VGPRs)
typedef __attribute__((ext_vector_type(4))) float f32x4;

// fp32 -> fp16 bits (round-to-nearest-even)
__device__ inline u16 f2h(float f) {
    return __half_as_ushort(__float2half(f));
}
__device__ inline float h2f(u16 u) {
    return __half2float(__ushort_as_half(u));
}
// fp16x2 (packed in a uint) -> float2
__device__ inline float2 h2f2(uint32 u) {
    __half2 h = *(__half2*)&u;
    return __half22float2(h);
}
__device__ inline uint32 packh2(float lo, float hi) {
    return (uint32)f2h(lo) | ((uint32)f2h(hi) << 16);
}

#define G1_BLOCKS 782                       // ceil(50000/64) rows of 64
#define FRONT_GRID (5 * G1_BLOCKS)          // 3910
#define BT_STRIDE 144

// ---------------------------------------------------------------------------
// prep: one-time weight transposes to global (consumed by front/gemm2 later
// in the stream -- separate launch, so ordering is guaranteed).
//   W1t_hi[n][k] = fp16(W1[k][n]);  W1t_lo = fp16 residual;  W2t[n][k] = fp16(W2[k][n])
// W1t_hi/lo live in the `sums` region (re-zeroed after front); W2t in its
// original slot. Workspace footprint byte-identical to the validated layout.
// ---------------------------------------------------------------------------
__global__ __launch_bounds__(256) void prep(const float* __restrict__ W1,
                                            const float* __restrict__ W2,
                                            u16* __restrict__ W1t_hi,
                                            u16* __restrict__ W1t_lo,
                                            u16* __restrict__ W2t)
{
    int i = blockIdx.x * 256 + threadIdx.x;       // grid 64 x 256 = 16384
    if (i >= HDIM * HDIM) return;
    int n = i >> 7, k = i & 127;
    float w1 = W1[k * HDIM + n];
    u16 h = f2h(w1);
    W1t_hi[i] = h;
    W1t_lo[i] = f2h(w1 - h2f(h));
    W2t[i] = f2h(W2[k * HDIM + n]);
}

// ---------------------------------------------------------------------------
// Fused front kernel (NO LDS). Role by blockIdx:
//   rem==0   : gemm1 via fp16 MFMA hi/lo split; B fragments read directly
//              from global W1t_hi/W1t_lo (64 KB, L2-resident across 782 blocks)
//   rem==1..4: bucket_edges (atomic-bound) -- co-scheduled at full occupancy
// gemm1 accuracy: x = A_hi + A_lo, W1 = B_hi + B_lo (fp16 residual split);
// acc = A_hi*B_hi + A_lo*B_hi + A_hi*B_lo -> fp32-equivalent (err ~2^-21).
// ---------------------------------------------------------------------------
__global__ __launch_bounds__(256) void front(const float* __restrict__ x,
                                             const u16* __restrict__ W1t_hi,
                                             const u16* __restrict__ W1t_lo,
                                             u16* __restrict__ bufA,
                                             const int* __restrict__ src,
                                             const int* __restrict__ dst,
                                             int* __restrict__ deg,
                                             u16* __restrict__ epad)
{
    const int tid = threadIdx.x;
    const int bid = blockIdx.x;
    const int grp = bid / 5, rem = bid % 5;

    if (rem != 0) {
        // ---- bucket_edges ----
        int e = (grp * 4 + (rem - 1)) * 256 + tid;
        if (e < N_EDGES) {
            int d   = dst[e];
            int pos = atomicAdd(&deg[d], 1);
            epad[d * MAXDEG + pos] = (u16)src[e];
        }
        return;
    }

    // ---- gemm1 via MFMA, B straight from global (L2) ----
    const int wave = tid >> 6, lane = tid & 63;
    const int rowbase = grp * 64 + wave * 16;
    if (rowbase >= N_NODES) return;           // 50000 % 16 == 0: whole strips
    const int n = lane & 15, q = lane >> 4;

    half8 a_hi[4], a_lo[4];
    const float* arow = x + (size_t)(rowbase + n) * HDIM;
    #pragma unroll
    for (int kc = 0; kc < 4; ++kc) {
        float4 lo4 = *(const float4*)(arow + kc * 32 + q * 8);
        float4 hi4 = *(const float4*)(arow + kc * 32 + q * 8 + 4);
        float f[8] = {lo4.x, lo4.y, lo4.z, lo4.w, hi4.x, hi4.y, hi4.z, hi4.w};
        half8 ah, al;
        #pragma unroll
        for (int e = 0; e < 8; ++e) {
            _Float16 h = (_Float16)f[e];
            ah[e] = h;
            al[e] = (_Float16)(f[e] - (float)h);
        }
        a_hi[kc] = ah; a_lo[kc] = al;
    }

    #pragma unroll
    for (int t = 0; t < 8; ++t) {
        f32x4 acc = {0.f, 0.f, 0.f, 0.f};
        const int brow = (t * 16 + n) * HDIM + q * 8;
        #pragma unroll
        for (int kc = 0; kc < 4; ++kc) {
            half8 bh = *(const half8*)&W1t_hi[brow + kc * 32];
            half8 bl = *(const half8*)&W1t_lo[brow + kc * 32];
            acc = __builtin_amdgcn_mfma_f32_16x16x32_f16(a_hi[kc], bh, acc, 0, 0, 0);
            acc = __builtin_amdgcn_mfma_f32_16x16x32_f16(a_lo[kc], bh, acc, 0, 0, 0);
            acc = __builtin_amdgcn_mfma_f32_16x16x32_f16(a_hi[kc], bl, acc, 0, 0, 0);
        }
        #pragma unroll
        for (int r = 0; r < 4; ++r) {
            int grow = rowbase + q * 4 + r;   // C/D: col=lane&15, row=quad*4+reg
            bufA[(size_t)grow * HDIM + t * 16 + n] = f2h(acc[r]);
        }
    }
}

// ---------------------------------------------------------------------------
// Layer-2 GEMM via fp16 MFMA 16x16x32.  Y[n][:] = A[n][:] @ W2  (A,Y fp16).
// W2t is pre-transposed fp16 [n][k].  Block: 256 thr = 4 waves x 16 rows.
// B staged in LDS, stride 144 (slot-uniform for ds_read_b128);
// A-fragments straight from global (16B/lane, sector-coalesced).
// ---------------------------------------------------------------------------
__global__ __launch_bounds__(256) void gemm2_mfma(const u16* __restrict__ A,
                                                  const u16* __restrict__ W2t,
                                                  u16* __restrict__ Y, int nrows)
{
    __shared__ u16 bt[HDIM * BT_STRIDE];
    const int tid = threadIdx.x;
    // stage W2t (dense 128x128 fp16) -> LDS stride 144, vectorized 16B
    for (int i = tid; i < HDIM * HDIM / 8; i += 256) {
        int n  = i >> 4;
        int k8 = (i & 15) << 3;
        *(uint4*)&bt[n * BT_STRIDE + k8] = *(const uint4*)&W2t[n * HDIM + k8];
    }
    __syncthreads();

    const int wave = tid >> 6, lane = tid & 63;
    const int rowbase = blockIdx.x * 64 + wave * 16;
    if (rowbase >= nrows) return;                   // 50000 % 16 == 0: whole strips
    const int n = lane & 15, q = lane >> 4;

    half8 a[4];
    const u16* arow = A + (size_t)(rowbase + n) * HDIM;
    #pragma unroll
    for (int kc = 0; kc < 4; ++kc)
        a[kc] = *(const half8*)(arow + kc * 32 + q * 8);

    #pragma unroll
    for (int t = 0; t < 8; ++t) {
        f32x4 acc = {0.f, 0.f, 0.f, 0.f};
        #pragma unroll
        for (int kc = 0; kc < 4; ++kc) {
            half8 b = *(const half8*)&bt[(t * 16 + n) * BT_STRIDE + kc * 32 + q * 8];
            acc = __builtin_amdgcn_mfma_f32_16x16x32_f16(a[kc], b, acc, 0, 0, 0);
        }
        #pragma unroll
        for (int r = 0; r < 4; ++r) {
            int grow = rowbase + q * 4 + r;          // C/D: col=lane&15, row=quad*4+reg
            Y[(size_t)grow * HDIM + t * 16 + n] = f2h(acc[r]);
        }
    }
}

// ---------------------------------------------------------------------------
// Padded-bucket gather + self-loop + bias + BN(eval) + ReLU, fused. fp16 h.
// One node/wave; quarter-wave per edge (lane: 8 channels, 16B load);
// 2x unrolled (8 edges in flight); per-edge rsqrt fused (no dis array).
// ---------------------------------------------------------------------------
__global__ __launch_bounds__(256) void gather_bn_relu(const u16* __restrict__ h,
                                                      const u16* __restrict__ epad,
                                                      const int* __restrict__ deg,
                                                      const float* __restrict__ b,
                                                      const float* __restrict__ gamma,
                                                      const float* __restrict__ beta,
                                                      const float* __restrict__ mean,
                                                      const float* __restrict__ var,
                                                      u16* __restrict__ out, int n)
{
    int node = blockIdx.x * 4 + (threadIdx.x >> 6);
    if (node >= n) return;
    const int lane = threadIdx.x & 63;
    const int q    = lane >> 4;          // quarter: which edge of the 4
    const int ci   = (lane & 15) << 3;   // 8 channels per lane
    const int cnt_e = deg[node];
    const float dd  = rsqrtf((float)cnt_e + 1.0f);

    // self-row load early (independent, hides latency)
    uint4 hv = *(const uint4*)(h + (size_t)node * HDIM + ci);

    // preload this node's edge list: lane l owns edge l (cnt_e <= 64)
    int   s_all  = 0;
    float nm_all = 0.f;
    if (lane < cnt_e) {
        s_all  = epad[node * MAXDEG + lane];
        nm_all = rsqrtf((float)deg[s_all] + 1.0f) * dd;
    }

    float acc[8] = {0.f, 0.f, 0.f, 0.f, 0.f, 0.f, 0.f, 0.f};
    int j = q;
    for (; j + 4 < cnt_e; j += 8) {
        int   s0 = __shfl(s_all, j);     float nm0 = __shfl(nm_all, j);
        int   s1 = __shfl(s_all, j + 4); float nm1 = __shfl(nm_all, j + 4);
        uint4 v0 = *(const uint4*)(h + (size_t)s0 * HDIM + ci);
        uint4 v1 = *(const uint4*)(h + (size_t)s1 * HDIM + ci);
        float2 f0 = h2f2(v0.x), f1 = h2f2(v0.y), f2 = h2f2(v0.z), f3 = h2f2(v0.w);
        acc[0] += f0.x * nm0; acc[1] += f0.y * nm0;
        acc[2] += f1.x * nm0; acc[3] += f1.y * nm0;
        acc[4] += f2.x * nm0; acc[5] += f2.y * nm0;
        acc[6] += f3.x * nm0; acc[7] += f3.y * nm0;
        float2 g0 = h2f2(v1.x), g1 = h2f2(v1.y), g2 = h2f2(v1.z), g3 = h2f2(v1.w);
        acc[0] += g0.x * nm1; acc[1] += g0.y * nm1;
        acc[2] += g1.x * nm1; acc[3] += g1.y * nm1;
        acc[4] += g2.x * nm1; acc[5] += g2.y * nm1;
        acc[6] += g3.x * nm1; acc[7] += g3.y * nm1;
    }
    if (j < cnt_e) {
        int   s0 = __shfl(s_all, j); float nm0 = __shfl(nm_all, j);
        uint4 v0 = *(const uint4*)(h + (size_t)s0 * HDIM + ci);
        float2 f0 = h2f2(v0.x), f1 = h2f2(v0.y), f2 = h2f2(v0.z), f3 = h2f2(v0.w);
        acc[0] += f0.x * nm0; acc[1] += f0.y * nm0;
        acc[2] += f1.x * nm0; acc[3] += f1.y * nm0;
        acc[4] += f2.x * nm0; acc[5] += f2.y * nm0;
        acc[6] += f3.x * nm0; acc[7] += f3.y * nm0;
    }
    #pragma unroll
    for (int k = 0; k < 8; ++k) {
        acc[k] += __shfl_xor(acc[k], 16);
        acc[k] += __shfl_xor(acc[k], 32);
    }

    if (q == 0) {
        float2 g0 = h2f2(hv.x), g1 = h2f2(hv.y), g2 = h2f2(hv.z), g3 = h2f2(hv.w);
        float dd2 = dd * dd;
        float a[8] = {acc[0] + g0.x * dd2, acc[1] + g0.y * dd2,
                      acc[2] + g1.x * dd2, acc[3] + g1.y * dd2,
                      acc[4] + g2.x * dd2, acc[5] + g2.y * dd2,
                      acc[6] + g3.x * dd2, acc[7] + g3.y * dd2};
        float o[8];
        #pragma unroll
        for (int k = 0; k < 8; ++k) {
            int c = ci + k;
            float sc = gamma[c] * rsqrtf(var[c] + BN_EPS);
            float r  = (a[k] + b[c] - mean[c]) * sc + beta[c];
            o[k] = fmaxf(r, 0.f);
        }
        uint4 ov;
        ov.x = packh2(o[0], o[1]); ov.y = packh2(o[2], o[3]);
        ov.z = packh2(o[4], o[5]); ov.w = packh2(o[6], o[7]);
        *(uint4*)(out + (size_t)node * HDIM + ci) = ov;
    }
}

// ---------------------------------------------------------------------------
// Pool: sums[batch[n]][c] += h[n][c] (fp16 h, fp32 sums); batch sorted.
// Also accumulates per-graph node counts (thread 0 of each block).
// ---------------------------------------------------------------------------
__global__ __launch_bounds__(128) void pool_sum(const u16* __restrict__ h,
                                                const int* __restrict__ batch,
                                                float* __restrict__ sums,
                                                float* __restrict__ cnt, int n)
{
    int c  = threadIdx.x;
    int n0 = blockIdx.x * 32;
    if (n0 >= n) return;
    int nend = min(n0 + 32, n);
    int curg = batch[n0];
    float acc = 0.f;
    int run = 0;
    for (int i = n0; i < nend; ++i) {
        int g   = batch[i];
        float v = __half2float(__ushort_as_half(h[(size_t)i * HDIM + c]));
        if (g != curg) {
            atomicAdd(&sums[(size_t)curg * HDIM + c], acc);
            if (c == 0) atomicAdd(&cnt[curg], (float)run);
            acc = 0.f; run = 0; curg = g;
        }
        acc += v; run++;
    }
    atomicAdd(&sums[(size_t)curg * HDIM + c], acc);
    if (c == 0) atomicAdd(&cnt[curg], (float)run);
}

// ---------------------------------------------------------------------------
// out[g][c] = (sums[g]/max(cnt[g],1)) . Wlin[:,c] + blin[c]
// ---------------------------------------------------------------------------
__global__ __launch_bounds__(128) void final_lin(const float* __restrict__ sums,
                                                 const float* __restrict__ cnt,
                                                 const float* __restrict__ Wlin,
                                                 const float* __restrict__ blin,
                                                 float* __restrict__ out)
{
    __shared__ float red[NCLS][2];
    int g = blockIdx.x;
    int t = threadIdx.x;
    float ic = 1.f / fmaxf(cnt[g], 1.f);
    float v  = sums[(size_t)g * HDIM + t] * ic;
    float p[NCLS];
    #pragma unroll
    for (int c = 0; c < NCLS; ++c) p[c] = v * Wlin[t * NCLS + c];
    #pragma unroll
    for (int c = 0; c < NCLS; ++c) {
        float x = p[c];
        for (int off = 32; off > 0; off >>= 1) x += __shfl_down(x, off);
        if ((t & 63) == 0) red[c][t >> 6] = x;
    }
    __syncthreads();
    if (t < NCLS) out[g * NCLS + t] = red[t][0] + red[t][1] + blin[t];
}

// ---------------------------------------------------------------------------
extern "C" void kernel_launch(void* const* d_in, const int* in_sizes, int n_in,
                              void* d_out, int out_size, void* d_ws, size_t ws_size,
                              hipStream_t stream)
{
    const float* x     = (const float*)d_in[0];
    const int*   ei    = (const int*)d_in[1];
    const int*   srcp  = ei;
    const int*   dstp  = ei + N_EDGES;
    const int*   batch = (const int*)d_in[2];
    const float* W1    = (const float*)d_in[3];
    const float* b1    = (const float*)d_in[4];
    const float* g1    = (const float*)d_in[5];
    const float* be1   = (const float*)d_in[6];
    const float* m1    = (const float*)d_in[7];
    const float* v1    = (const float*)d_in[8];
    const float* W2    = (const float*)d_in[9];
    const float* b2    = (const float*)d_in[10];
    const float* g2    = (const float*)d_in[11];
    const float* be2   = (const float*)d_in[12];
    const float* m2    = (const float*)d_in[13];
    const float* v2    = (const float*)d_in[14];
    const float* Wlin  = (const float*)d_in[15];
    const float* blin  = (const float*)d_in[16];
    float*       out   = (float*)d_out;

    // workspace layout -- byte-identical footprint to the validated layout:
    // [deg int | cnt f32 | sums f32 | bufA fp16 | bufB fp16 | epad u16 | W2t fp16]
    // W1t_hi/lo (64 KB) BORROW the sums region (256 KB): written by prep,
    // consumed by front, then sums is re-zeroed before pool_sum.
    int*   deg    = (int*)d_ws;
    float* cnt    = (float*)(deg + N_NODES);
    float* sums   = cnt + NGRAPH;
    u16*   W1t_hi = (u16*)sums;                         // 32 KB
    u16*   W1t_lo = W1t_hi + (size_t)HDIM * HDIM;       // 32 KB (<= 256 KB region)
    u16*   bufA   = (u16*)(sums + (size_t)NGRAPH * HDIM);
    u16*   bufB   = bufA + (size_t)N_NODES * HDIM;
    u16*   epad   = bufB + (size_t)N_NODES * HDIM;
    u16*   W2t    = epad + (size_t)N_NODES * MAXDEG;    // original slot

    // zero deg + cnt (sums is zeroed later, after front consumes W1t)
    hipMemsetAsync(deg, 0, (N_NODES + NGRAPH) * sizeof(float), stream);

    // ---- one-time weight transposes (ordered before front by the stream) ----
    prep<<<(HDIM * HDIM + 255) / 256, 256, 0, stream>>>(W1, W2, W1t_hi, W1t_lo, W2t);

    // ---- fused front: bucket + gemm1 (MFMA hi/lo, B from L2, no LDS) ----
    front<<<FRONT_GRID, 256, 0, stream>>>(x, W1t_hi, W1t_lo, bufA,
                                          srcp, dstp, deg, epad);

    // re-zero sums region (W1t no longer needed; pool_sum atomics need 0s)
    hipMemsetAsync(sums, 0, (size_t)NGRAPH * HDIM * sizeof(float), stream);

    const int gather_blocks = (N_NODES + 3) / 4;

    // ---- layer 1 aggregation ----
    gather_bn_relu<<<gather_blocks, 256, 0, stream>>>(bufA, epad, deg,
                                                      b1, g1, be1, m1, v1, bufB, N_NODES);
    // ---- layer 2 ----
    gemm2_mfma<<<(N_NODES + 63) / 64, 256, 0, stream>>>(bufB, W2t, bufA, N_NODES);
    gather_bn_relu<<<gather_blocks, 256, 0, stream>>>(bufA, epad, deg,
                                                      b2, g2, be2, m2, v2, bufB, N_NODES);
    // ---- pool + head ----
    pool_sum<<<(N_NODES + 31) / 32, 128, 0, stream>>>(bufB, batch, sums, cnt, N_NODES);
    final_lin<<<NGRAPH, 128, 0, stream>>>(sums, cnt, Wlin, blin, out);
}